// Round 4
// baseline (887.110 us; speedup 1.0000x reference)
//
#include <hip/hip_runtime.h>
#include <hip/hip_bf16.h>

#define BATCH 512
#define TIN   256
#define TOUT  128
#define VOC   256
#define NZ    1024
#define EHID  64
#define DHID  128
#define SDIM  32

__device__ __forceinline__ float bf2f(unsigned short u) {
  return __uint_as_float(((unsigned)u) << 16);
}
__device__ __forceinline__ unsigned short f2bf(float f) {
  unsigned u = __float_as_uint(f);
  u = u + 0x7FFFu + ((u >> 16) & 1u);
  return (unsigned short)(u >> 16);
}
__device__ __forceinline__ float sigf(float x) { return 1.0f / (1.0f + __expf(-x)); }
__device__ __forceinline__ float tanh_(float x) { return 1.0f - 2.0f / (1.0f + __expf(2.0f * x)); }

// ---------------------------------------------------------------------------
// Build transposed + bias-folded gather tables (all f32).
//  blk 0..255  : WxT[v][g]   = enc_Wih[g][v] + enc_b[g]   (v<256, g<256)
//  blk 256..511: WdecT[v][g] = dec_Wih[g][v] + dec_b[g]   (g<512)
//  blk 512..639: WdT[k][v]   = out_W[v][k]                (k<128)
// ---------------------------------------------------------------------------
__global__ void k_prep(const float* __restrict__ enc_Wih, const float* __restrict__ enc_b,
                       const float* __restrict__ dec_Wih, const float* __restrict__ dec_b,
                       const float* __restrict__ out_W,
                       float* __restrict__ WxT, float* __restrict__ WdecT,
                       float* __restrict__ WdT) {
  int blk = blockIdx.x, tid = threadIdx.x;
  if (blk < 256) {
    if (tid < 256)
      WxT[blk * 256 + tid] = enc_Wih[(size_t)tid * (VOC + NZ) + blk] + enc_b[tid];
  } else if (blk < 512) {
    int v = blk - 256;
    WdecT[v * 512 + tid] = dec_Wih[(size_t)tid * VOC + v] + dec_b[tid];
  } else {
    int k = blk - 512;
    if (tid < 256)
      WdT[k * 256 + tid] = out_W[(size_t)tid * (DHID + SDIM) + k];
  }
}

// ---------------------------------------------------------------------------
// One-hot (f32) -> index via wave min-reduce. One wave per position.
// ---------------------------------------------------------------------------
__global__ void k_findidx(const float* __restrict__ src, int n_pos,
                          int* __restrict__ out) {
  int pos = blockIdx.x * 4 + (threadIdx.x >> 6);
  int lane = threadIdx.x & 63;
  if (pos >= n_pos) return;
  float4 v = ((const float4*)src)[(size_t)pos * 64 + lane];
  int comp = v.x > 0.5f ? 0 : (v.y > 0.5f ? 1 : (v.z > 0.5f ? 2 : 3));
  bool hit = (v.x > 0.5f) || (v.y > 0.5f) || (v.z > 0.5f) || (v.w > 0.5f);
  int cand = hit ? lane * 4 + comp : (1 << 30);
#pragma unroll
  for (int off = 32; off > 0; off >>= 1) {
    int o = __shfl_xor(cand, off);
    cand = cand < o ? cand : o;
  }
  if (lane == 0) out[pos] = cand < VOC ? cand : VOC - 1;
}

// ---------------------------------------------------------------------------
// gxc[b][g] = zia[b] . Wz[g]  (Wz = enc_Wih[:, V:]).  One batch per block.
// ---------------------------------------------------------------------------
__global__ __launch_bounds__(256) void k_gx_const(
    const float* __restrict__ zia, const float* __restrict__ enc_Wih,
    float* __restrict__ gxc) {
  __shared__ float zs[NZ];
  int b = blockIdx.x, g = threadIdx.x;
  ((float4*)zs)[g] = ((const float4*)(zia + (size_t)b * NZ))[g];
  __syncthreads();
  float acc = 0.0f;
  const float4* wr = (const float4*)(enc_Wih + (size_t)g * (VOC + NZ) + VOC);
  const float4* z4 = (const float4*)zs;
#pragma unroll 8
  for (int k4 = 0; k4 < NZ / 4; ++k4) {
    float4 w = wr[k4], z = z4[k4];
    acc += w.x * z.x + w.y * z.y + w.z * z.z + w.w * z.w;
  }
  gxc[b * 256 + g] = acc;
}

// ---------------------------------------------------------------------------
// Encoder LSTM scan. One block per batch; thread = gate g (256 threads).
// ---------------------------------------------------------------------------
__global__ __launch_bounds__(256) void k_enc_scan(
    const float* __restrict__ enc_Whh, const float* __restrict__ WxT,
    const float* __restrict__ gxc, const int* __restrict__ enc_idx,
    float* __restrict__ h_enc) {
  __shared__ float h_s[EHID];
  __shared__ float part[256];
  __shared__ int idx_s[TIN];
  int b = blockIdx.x, g = threadIdx.x;

  float w[EHID];
#pragma unroll
  for (int k = 0; k < EHID; ++k) w[k] = enc_Whh[(size_t)g * EHID + k];
  float gxcr = gxc[b * 256 + g];
  if (g < EHID) h_s[g] = 0.0f;
  idx_s[g] = enc_idx[b * TIN + g];  // 256 threads, 256 steps
  __syncthreads();

  float c = 0.0f;
  for (int t = 0; t < TIN; ++t) {
    float acc = WxT[idx_s[t] * 256 + g] + gxcr;
#pragma unroll
    for (int k = 0; k < EHID; ++k) acc += w[k] * h_s[k];
    part[g] = acc;
    __syncthreads();
    if (g < EHID) {
      float i_ = part[g];
      float f_ = part[EHID + g];
      float g_ = part[2 * EHID + g];
      float o_ = part[3 * EHID + g];
      c = sigf(f_) * c + sigf(i_) * tanh_(g_);
      h_s[g] = sigf(o_) * tanh_(c);
    }
    __syncthreads();
  }
  if (g < EHID) h_enc[b * EHID + g] = h_s[g];
}

// ---------------------------------------------------------------------------
// sg -> fortza_new (f32, to d_out tail) and fout[b][v] = out_b[v] + fn.Wf[v].
// One block per batch, 256 threads.
// ---------------------------------------------------------------------------
__global__ __launch_bounds__(256) void k_sg_fortza(
    const float* __restrict__ h_enc, const float* __restrict__ fortza,
    const float* __restrict__ sg_W, const float* __restrict__ sg_b,
    const float* __restrict__ out_W, const float* __restrict__ out_b,
    float* __restrict__ out_fortza, float* __restrict__ fout) {
  __shared__ float hf[EHID], fz[SDIM], sg_s[2 * SDIM], fn[SDIM];
  int b = blockIdx.x, tid = threadIdx.x;
  if (tid < EHID) hf[tid] = h_enc[b * EHID + tid];
  if (tid >= EHID && tid < EHID + SDIM)
    fz[tid - EHID] = fortza[(size_t)b * SDIM + (tid - EHID)];
  __syncthreads();
  if (tid < 2 * SDIM) {
    float acc = sg_b[tid];
    const float* row = sg_W + (size_t)tid * (EHID + SDIM);
    for (int k = 0; k < EHID; ++k) acc += hf[k] * row[k];
    for (int j = 0; j < SDIM; ++j) acc += fz[j] * row[EHID + j];
    sg_s[tid] = acc;
  }
  __syncthreads();
  if (tid < SDIM) {
    float gate = sigf(sg_s[tid]);
    float upd = tanh_(sg_s[SDIM + tid]);
    float v = gate * fz[tid] + (1.0f - gate) * upd;
    fn[tid] = v;
    out_fortza[(size_t)b * SDIM + tid] = v;
  }
  __syncthreads();
  {
    float acc = out_b[tid];
    const float* row = out_W + (size_t)tid * (DHID + SDIM) + DHID;
    for (int j = 0; j < SDIM; ++j) acc += fn[j] * row[j];
    fout[b * VOC + tid] = acc;
  }
}

// ---------------------------------------------------------------------------
// dh0[b][v] = tanh([h_enc, zia] . Wc_W[v] + Wc_b[v]).  One batch per block.
// ---------------------------------------------------------------------------
__global__ __launch_bounds__(128) void k_dh0(
    const float* __restrict__ h_enc, const float* __restrict__ zia,
    const float* __restrict__ Wc_W, const float* __restrict__ Wc_b,
    float* __restrict__ dh0) {
  __shared__ float xs[EHID + NZ];
  int b = blockIdx.x, v = threadIdx.x;
  if (v < EHID) xs[v] = h_enc[b * EHID + v];
  for (int i = v; i < NZ / 4; i += 128)
    ((float4*)(xs + EHID))[i] = ((const float4*)(zia + (size_t)b * NZ))[i];
  __syncthreads();
  float acc = Wc_b[v];
  const float4* wr = (const float4*)(Wc_W + (size_t)v * (EHID + NZ));
  const float4* x4 = (const float4*)xs;
#pragma unroll 8
  for (int k4 = 0; k4 < (EHID + NZ) / 4; ++k4) {
    float4 w = wr[k4], x = x4[k4];
    acc += w.x * x.x + w.y * x.y + w.z * x.z + w.w * x.w;
  }
  dh0[b * DHID + v] = tanh_(acc);
}

// ---------------------------------------------------------------------------
// Decoder LSTM scan. One block per batch; thread = gate g (512 threads).
// Stores dhs[t][b][h] as bf16 (ws compression; error ~1e-3 << threshold).
// ---------------------------------------------------------------------------
__global__ __launch_bounds__(512) void k_dec_scan(
    const float* __restrict__ dec_Whh, const float* __restrict__ WdecT,
    const int* __restrict__ dec_idx, const float* __restrict__ dh0,
    unsigned short* __restrict__ dhs) {
  __shared__ float h_s[DHID];
  __shared__ float part[512];
  __shared__ int idx_s[TOUT];
  int b = blockIdx.x, g = threadIdx.x;

  float w[DHID];
#pragma unroll
  for (int k = 0; k < DHID; ++k) w[k] = dec_Whh[(size_t)g * DHID + k];
  if (g < DHID) h_s[g] = dh0[b * DHID + g];
  if (g < TOUT) idx_s[g] = dec_idx[b * TOUT + g];
  __syncthreads();

  float c = 0.0f;
  for (int t = 0; t < TOUT; ++t) {
    float acc = WdecT[idx_s[t] * 512 + g];
#pragma unroll
    for (int k = 0; k < DHID; ++k) acc += w[k] * h_s[k];
    part[g] = acc;
    __syncthreads();
    if (g < DHID) {
      float i_ = part[g];
      float f_ = part[DHID + g];
      float g_ = part[2 * DHID + g];
      float o_ = part[3 * DHID + g];
      c = sigf(f_) * c + sigf(i_) * tanh_(g_);
      float h = sigf(o_) * tanh_(c);
      h_s[g] = h;
      dhs[(size_t)t * BATCH * DHID + (size_t)b * DHID + g] = f2bf(h);
    }
    __syncthreads();
  }
}

// ---------------------------------------------------------------------------
// logits[b][t][v] = dhs[t][b][:] . WdT[:][v] + fout[b][v];  f32 store.
// Block: 64 rows (one t, 64 consecutive b) x 256 v.  Thread: 4v x 16m tile.
// ---------------------------------------------------------------------------
__global__ __launch_bounds__(256) void k_logits(const unsigned short* __restrict__ dhs,
                                                const float* __restrict__ WdT,
                                                const float* __restrict__ fout,
                                                float* __restrict__ out) {
  __shared__ float s[DHID * 64];  // k-major: s[k*64 + m]
  int r0 = blockIdx.x * 64;
  int t = r0 / BATCH;
  int b0 = r0 % BATCH;
  int tid = threadIdx.x;
  for (int i = tid; i < 64 * DHID; i += 256) {
    int m = i >> 7;
    int k = i & 127;
    s[k * 64 + m] = bf2f(dhs[(size_t)(r0 + m) * DHID + k]);
  }
  __syncthreads();
  int v4 = tid & 63;  // v = v4*4 .. +3
  int mg = tid >> 6;  // m = mg*16 .. +15
  float4 acc[16];
#pragma unroll
  for (int m = 0; m < 16; ++m) acc[m] = make_float4(0.f, 0.f, 0.f, 0.f);
  for (int k = 0; k < DHID; ++k) {
    float4 wv = ((const float4*)(WdT + k * 256))[v4];
    const float4* sk = (const float4*)(s + k * 64 + mg * 16);
#pragma unroll
    for (int j = 0; j < 4; ++j) {
      float4 h4 = sk[j];
      acc[j * 4 + 0].x += h4.x * wv.x; acc[j * 4 + 0].y += h4.x * wv.y;
      acc[j * 4 + 0].z += h4.x * wv.z; acc[j * 4 + 0].w += h4.x * wv.w;
      acc[j * 4 + 1].x += h4.y * wv.x; acc[j * 4 + 1].y += h4.y * wv.y;
      acc[j * 4 + 1].z += h4.y * wv.z; acc[j * 4 + 1].w += h4.y * wv.w;
      acc[j * 4 + 2].x += h4.z * wv.x; acc[j * 4 + 2].y += h4.z * wv.y;
      acc[j * 4 + 2].z += h4.z * wv.z; acc[j * 4 + 2].w += h4.z * wv.w;
      acc[j * 4 + 3].x += h4.w * wv.x; acc[j * 4 + 3].y += h4.w * wv.y;
      acc[j * 4 + 3].z += h4.w * wv.z; acc[j * 4 + 3].w += h4.w * wv.w;
    }
  }
#pragma unroll
  for (int m = 0; m < 16; ++m) {
    int bb = b0 + mg * 16 + m;
    float4 fo = ((const float4*)(fout + bb * VOC))[v4];
    float4 r;
    r.x = acc[m].x + fo.x;
    r.y = acc[m].y + fo.y;
    r.z = acc[m].z + fo.z;
    r.w = acc[m].w + fo.w;
    ((float4*)(out + ((size_t)bb * TOUT + t) * VOC))[v4] = r;
  }
}

// ---------------------------------------------------------------------------
extern "C" void kernel_launch(void* const* d_in, const int* in_sizes, int n_in,
                              void* d_out, int out_size, void* d_ws, size_t ws_size,
                              hipStream_t stream) {
  const float* inp_onehot = (const float*)d_in[0];
  const float* zia     = (const float*)d_in[1];
  const float* tgt     = (const float*)d_in[2];
  const float* fortza  = (const float*)d_in[3];
  const float* enc_Wih = (const float*)d_in[4];
  const float* enc_Whh = (const float*)d_in[5];
  const float* enc_b   = (const float*)d_in[6];
  const float* sg_W    = (const float*)d_in[7];
  const float* sg_b    = (const float*)d_in[8];
  const float* Wc_W    = (const float*)d_in[9];
  const float* Wc_b    = (const float*)d_in[10];
  const float* dec_Wih = (const float*)d_in[11];
  const float* dec_Whh = (const float*)d_in[12];
  const float* dec_b   = (const float*)d_in[13];
  const float* out_W   = (const float*)d_in[14];
  const float* out_b   = (const float*)d_in[15];
  float* out = (float*)d_out;

  float* ws = (float*)d_ws;
  int* enc_idx  = (int*)d_ws;              // 131072 ints
  int* dec_idx  = enc_idx + BATCH * TIN;   //  65536 ints
  float* WxT    = ws + 196608;             //  65536 f
  float* WdecT  = ws + 262144;             // 131072 f
  float* WdT    = ws + 393216;             //  32768 f
  float* gxc    = ws + 425984;             // 131072 f
  float* h_enc  = ws + 557056;             //  32768 f
  float* dh0    = ws + 589824;             //  65536 f
  float* fout   = ws + 655360;             // 131072 f
  unsigned short* dhs = (unsigned short*)(ws + 786432);  // 8388608 u16; total ~19.9 MB

  k_prep<<<640, 512, 0, stream>>>(enc_Wih, enc_b, dec_Wih, dec_b, out_W, WxT, WdecT, WdT);
  k_findidx<<<BATCH * TIN / 4, 256, 0, stream>>>(inp_onehot, BATCH * TIN, enc_idx);
  k_findidx<<<BATCH * TOUT / 4, 256, 0, stream>>>(tgt, BATCH * TOUT, dec_idx);
  k_gx_const<<<BATCH, 256, 0, stream>>>(zia, enc_Wih, gxc);
  k_enc_scan<<<BATCH, 256, 0, stream>>>(enc_Whh, WxT, gxc, enc_idx, h_enc);
  k_sg_fortza<<<BATCH, 256, 0, stream>>>(h_enc, fortza, sg_W, sg_b, out_W, out_b,
                                         out + (size_t)BATCH * TOUT * VOC, fout);
  k_dh0<<<BATCH, 128, 0, stream>>>(h_enc, zia, Wc_W, Wc_b, dh0);
  k_dec_scan<<<BATCH, 512, 0, stream>>>(dec_Whh, WdecT, dec_idx, dh0, dhs);
  k_logits<<<TOUT * BATCH / 64, 256, 0, stream>>>(dhs, WdT, fout, out);
}

// Round 5
// 629.499 us; speedup vs baseline: 1.4092x; 1.4092x over previous
//
#include <hip/hip_runtime.h>
#include <hip/hip_bf16.h>

#define BATCH 512
#define TIN   256
#define TOUT  128
#define VOC   256
#define NZ    1024
#define EHID  64
#define DHID  128
#define SDIM  32

typedef __attribute__((ext_vector_type(8))) short bf16x8;
typedef __attribute__((ext_vector_type(4))) float f32x4;

__device__ __forceinline__ float bf2f(unsigned short u) {
  return __uint_as_float(((unsigned)u) << 16);
}
__device__ __forceinline__ unsigned short f2bf(float f) {
  unsigned u = __float_as_uint(f);
  u = u + 0x7FFFu + ((u >> 16) & 1u);
  return (unsigned short)(u >> 16);
}
__device__ __forceinline__ float sigf(float x) { return 1.0f / (1.0f + __expf(-x)); }
__device__ __forceinline__ float tanh_(float x) { return 1.0f - 2.0f / (1.0f + __expf(2.0f * x)); }

__device__ __forceinline__ bf16x8 pack8(float4 a, float4 b) {
  bf16x8 r;
  r[0] = (short)f2bf(a.x); r[1] = (short)f2bf(a.y);
  r[2] = (short)f2bf(a.z); r[3] = (short)f2bf(a.w);
  r[4] = (short)f2bf(b.x); r[5] = (short)f2bf(b.y);
  r[6] = (short)f2bf(b.z); r[7] = (short)f2bf(b.w);
  return r;
}

// ---------------------------------------------------------------------------
// Build transposed + bias-folded gather tables (all f32).
// ---------------------------------------------------------------------------
__global__ void k_prep(const float* __restrict__ enc_Wih, const float* __restrict__ enc_b,
                       const float* __restrict__ dec_Wih, const float* __restrict__ dec_b,
                       const float* __restrict__ out_W,
                       float* __restrict__ WxT, float* __restrict__ WdecT,
                       float* __restrict__ WdT) {
  int blk = blockIdx.x, tid = threadIdx.x;
  if (blk < 256) {
    if (tid < 256)
      WxT[blk * 256 + tid] = enc_Wih[(size_t)tid * (VOC + NZ) + blk] + enc_b[tid];
  } else if (blk < 512) {
    int v = blk - 256;
    WdecT[v * 512 + tid] = dec_Wih[(size_t)tid * VOC + v] + dec_b[tid];
  } else {
    int k = blk - 512;
    if (tid < 256)
      WdT[k * 256 + tid] = out_W[(size_t)tid * (DHID + SDIM) + k];
  }
}

// ---------------------------------------------------------------------------
// One-hot (f32) -> index via wave min-reduce. One wave per position.
// ---------------------------------------------------------------------------
__global__ void k_findidx(const float* __restrict__ src, int n_pos,
                          int* __restrict__ out) {
  int pos = blockIdx.x * 4 + (threadIdx.x >> 6);
  int lane = threadIdx.x & 63;
  if (pos >= n_pos) return;
  float4 v = ((const float4*)src)[(size_t)pos * 64 + lane];
  int comp = v.x > 0.5f ? 0 : (v.y > 0.5f ? 1 : (v.z > 0.5f ? 2 : 3));
  bool hit = (v.x > 0.5f) || (v.y > 0.5f) || (v.z > 0.5f) || (v.w > 0.5f);
  int cand = hit ? lane * 4 + comp : (1 << 30);
#pragma unroll
  for (int off = 32; off > 0; off >>= 1) {
    int o = __shfl_xor(cand, off);
    cand = cand < o ? cand : o;
  }
  if (lane == 0) out[pos] = cand < VOC ? cand : VOC - 1;
}

// ---------------------------------------------------------------------------
// gxc[b][g] = zia[b] . Wz[g]  (Wz = enc_Wih[:, V:]).  One batch per block.
// ---------------------------------------------------------------------------
__global__ __launch_bounds__(256) void k_gx_const(
    const float* __restrict__ zia, const float* __restrict__ enc_Wih,
    float* __restrict__ gxc) {
  __shared__ float zs[NZ];
  int b = blockIdx.x, g = threadIdx.x;
  ((float4*)zs)[g] = ((const float4*)(zia + (size_t)b * NZ))[g];
  __syncthreads();
  float acc = 0.0f;
  const float4* wr = (const float4*)(enc_Wih + (size_t)g * (VOC + NZ) + VOC);
  const float4* z4 = (const float4*)zs;
#pragma unroll 8
  for (int k4 = 0; k4 < NZ / 4; ++k4) {
    float4 w = wr[k4], z = z4[k4];
    acc += w.x * z.x + w.y * z.y + w.z * z.z + w.w * z.w;
  }
  gxc[b * 256 + g] = acc;
}

// ---------------------------------------------------------------------------
// Encoder LSTM scan via MFMA. 128 blocks x 256 thr (4 waves).
// Block owns 4 batches mapped to A-rows {0,4,8,12}; wave w owns j-slice
// [w*16, w*16+16); its 4 N-tiles are the i/f/g/o gate tiles at that j-slice,
// so each lane holds i,f,g,o for (batch=quad, j=w*16+n) after the MFMAs.
// h double-buffered in LDS as bf16; ONE barrier per step.
// ---------------------------------------------------------------------------
#define ESTR 72
__global__ __launch_bounds__(256) void k_enc_scan_mfma(
    const float* __restrict__ enc_Whh, const float* __restrict__ WxT,
    const float* __restrict__ gxc, const int* __restrict__ enc_idx,
    float* __restrict__ h_enc) {
  __shared__ unsigned short hA[2][16 * ESTR];
  __shared__ int idx_s[4][TIN];
  int b0 = blockIdx.x * 4;
  int tid = threadIdx.x;
  int w = tid >> 6, lane = tid & 63, n = lane & 15, quad = lane >> 4;
  int j0 = w * 16, j = j0 + n;

  // B fragments: B[k][col=n] = enc_Whh[gate = ty*64 + j0 + n][k], bf16.
  bf16x8 Bf[4][2];
#pragma unroll
  for (int ty = 0; ty < 4; ++ty)
#pragma unroll
    for (int kb = 0; kb < 2; ++kb) {
      const float* src = enc_Whh + (size_t)(ty * 64 + j0 + n) * EHID + kb * 32 + quad * 8;
      float4 x = *(const float4*)src, y = *(const float4*)(src + 4);
      Bf[ty][kb] = pack8(x, y);
    }
  for (int i = tid; i < 16 * ESTR; i += 256) { hA[0][i] = 0; hA[1][i] = 0; }
  for (int i = tid; i < 4 * TIN; i += 256)
    idx_s[i >> 8][i & 255] = enc_idx[(size_t)(b0 + (i >> 8)) * TIN + (i & 255)];
  float gc[4];
#pragma unroll
  for (int ty = 0; ty < 4; ++ty) gc[ty] = gxc[(size_t)(b0 + quad) * 256 + ty * 64 + j];
  __syncthreads();

  float gx[4];
  {
    int id0 = idx_s[quad][0];
#pragma unroll
    for (int ty = 0; ty < 4; ++ty) gx[ty] = WxT[(size_t)id0 * 256 + ty * 64 + j];
  }
  float c0 = 0.0f, h = 0.0f;
  for (int t = 0; t < TIN; ++t) {
    const unsigned short* cur = hA[t & 1];
    bf16x8 a[2];
#pragma unroll
    for (int kb = 0; kb < 2; ++kb)
      a[kb] = *(const bf16x8*)(cur + n * ESTR + kb * 32 + quad * 8);
    // prefetch next step's input-side gates
    float gxn[4];
    int tn = (t + 1 < TIN) ? t + 1 : t;
    int idn = idx_s[quad][tn];
#pragma unroll
    for (int ty = 0; ty < 4; ++ty) gxn[ty] = WxT[(size_t)idn * 256 + ty * 64 + j];
    f32x4 acc[4];
#pragma unroll
    for (int ty = 0; ty < 4; ++ty) {
      f32x4 z; z[0] = gx[ty] + gc[ty]; z[1] = 0.f; z[2] = 0.f; z[3] = 0.f;
#pragma unroll
      for (int kb = 0; kb < 2; ++kb)
        z = __builtin_amdgcn_mfma_f32_16x16x32_bf16(a[kb], Bf[ty][kb], z, 0, 0, 0);
      acc[ty] = z;
    }
    // row 0 of each quad-group (= A-row quad*4) is the real batch.
    float gi = acc[0][0], gf = acc[1][0], gg = acc[2][0], go = acc[3][0];
    c0 = sigf(gf) * c0 + sigf(gi) * tanh_(gg);
    h = sigf(go) * tanh_(c0);
    hA[(t + 1) & 1][(quad * 4) * ESTR + j] = f2bf(h);
    gx[0] = gxn[0]; gx[1] = gxn[1]; gx[2] = gxn[2]; gx[3] = gxn[3];
    __syncthreads();
  }
  h_enc[(size_t)(b0 + quad) * EHID + j] = h;
}

// ---------------------------------------------------------------------------
// sg -> fortza_new (f32, to d_out tail) and fout[b][v] = out_b[v] + fn.Wf[v].
// ---------------------------------------------------------------------------
__global__ __launch_bounds__(256) void k_sg_fortza(
    const float* __restrict__ h_enc, const float* __restrict__ fortza,
    const float* __restrict__ sg_W, const float* __restrict__ sg_b,
    const float* __restrict__ out_W, const float* __restrict__ out_b,
    float* __restrict__ out_fortza, float* __restrict__ fout) {
  __shared__ float hf[EHID], fz[SDIM], sg_s[2 * SDIM], fn[SDIM];
  int b = blockIdx.x, tid = threadIdx.x;
  if (tid < EHID) hf[tid] = h_enc[b * EHID + tid];
  if (tid >= EHID && tid < EHID + SDIM)
    fz[tid - EHID] = fortza[(size_t)b * SDIM + (tid - EHID)];
  __syncthreads();
  if (tid < 2 * SDIM) {
    float acc = sg_b[tid];
    const float* row = sg_W + (size_t)tid * (EHID + SDIM);
    for (int k = 0; k < EHID; ++k) acc += hf[k] * row[k];
    for (int j = 0; j < SDIM; ++j) acc += fz[j] * row[EHID + j];
    sg_s[tid] = acc;
  }
  __syncthreads();
  if (tid < SDIM) {
    float gate = sigf(sg_s[tid]);
    float upd = tanh_(sg_s[SDIM + tid]);
    float v = gate * fz[tid] + (1.0f - gate) * upd;
    fn[tid] = v;
    out_fortza[(size_t)b * SDIM + tid] = v;
  }
  __syncthreads();
  {
    float acc = out_b[tid];
    const float* row = out_W + (size_t)tid * (DHID + SDIM) + DHID;
    for (int j = 0; j < SDIM; ++j) acc += fn[j] * row[j];
    fout[b * VOC + tid] = acc;
  }
}

// ---------------------------------------------------------------------------
// dh0[b][v] = tanh([h_enc, zia] . Wc_W[v] + Wc_b[v]).  One batch per block.
// ---------------------------------------------------------------------------
__global__ __launch_bounds__(128) void k_dh0(
    const float* __restrict__ h_enc, const float* __restrict__ zia,
    const float* __restrict__ Wc_W, const float* __restrict__ Wc_b,
    float* __restrict__ dh0) {
  __shared__ float xs[EHID + NZ];
  int b = blockIdx.x, v = threadIdx.x;
  if (v < EHID) xs[v] = h_enc[b * EHID + v];
  for (int i = v; i < NZ / 4; i += 128)
    ((float4*)(xs + EHID))[i] = ((const float4*)(zia + (size_t)b * NZ))[i];
  __syncthreads();
  float acc = Wc_b[v];
  const float4* wr = (const float4*)(Wc_W + (size_t)v * (EHID + NZ));
  const float4* x4 = (const float4*)xs;
#pragma unroll 8
  for (int k4 = 0; k4 < (EHID + NZ) / 4; ++k4) {
    float4 w = wr[k4], x = x4[k4];
    acc += w.x * x.x + w.y * x.y + w.z * x.z + w.w * x.w;
  }
  dh0[b * DHID + v] = tanh_(acc);
}

// ---------------------------------------------------------------------------
// Decoder LSTM scan via MFMA. 128 blocks x 512 thr (8 waves).
// Same scheme as encoder: 4 batches at A-rows {0,4,8,12}; wave w owns
// j-slice [w*16,+16) with its 4 gate-type tiles; K=128 -> 4 K-blocks.
// Stores dhs[t][b][h] as bf16.
// ---------------------------------------------------------------------------
#define DSTR 136
__global__ __launch_bounds__(512) void k_dec_scan_mfma(
    const float* __restrict__ dec_Whh, const float* __restrict__ WdecT,
    const int* __restrict__ dec_idx, const float* __restrict__ dh0,
    unsigned short* __restrict__ dhs) {
  __shared__ unsigned short hA[2][16 * DSTR];
  __shared__ int idx_s[4][TOUT];
  int b0 = blockIdx.x * 4;
  int tid = threadIdx.x;
  int w = tid >> 6, lane = tid & 63, n = lane & 15, quad = lane >> 4;
  int j0 = w * 16, j = j0 + n;

  bf16x8 Bf[4][4];
#pragma unroll
  for (int ty = 0; ty < 4; ++ty)
#pragma unroll
    for (int kb = 0; kb < 4; ++kb) {
      const float* src = dec_Whh + (size_t)(ty * 128 + j0 + n) * DHID + kb * 32 + quad * 8;
      float4 x = *(const float4*)src, y = *(const float4*)(src + 4);
      Bf[ty][kb] = pack8(x, y);
    }
  // init: buf0 real rows <- dh0 (bf16), everything else 0 (incl. buf1 garbage rows)
  for (int i = tid; i < 16 * DSTR; i += 512) {
    int m = i / DSTR, k = i - m * DSTR;
    float v = (k < DHID && (m & 3) == 0) ? dh0[(size_t)(b0 + (m >> 2)) * DHID + k] : 0.0f;
    hA[0][i] = f2bf(v);
    hA[1][i] = 0;
  }
  for (int i = tid; i < 4 * TOUT; i += 512)
    idx_s[i >> 7][i & 127] = dec_idx[(size_t)(b0 + (i >> 7)) * TOUT + (i & 127)];
  __syncthreads();

  float gx[4];
  {
    int id0 = idx_s[quad][0];
#pragma unroll
    for (int ty = 0; ty < 4; ++ty) gx[ty] = WdecT[(size_t)id0 * 512 + ty * 128 + j];
  }
  float c0 = 0.0f;
  for (int t = 0; t < TOUT; ++t) {
    const unsigned short* cur = hA[t & 1];
    bf16x8 a[4];
#pragma unroll
    for (int kb = 0; kb < 4; ++kb)
      a[kb] = *(const bf16x8*)(cur + n * DSTR + kb * 32 + quad * 8);
    float gxn[4];
    int tn = (t + 1 < TOUT) ? t + 1 : t;
    int idn = idx_s[quad][tn];
#pragma unroll
    for (int ty = 0; ty < 4; ++ty) gxn[ty] = WdecT[(size_t)idn * 512 + ty * 128 + j];
    f32x4 acc[4];
#pragma unroll
    for (int ty = 0; ty < 4; ++ty) {
      f32x4 z; z[0] = gx[ty]; z[1] = 0.f; z[2] = 0.f; z[3] = 0.f;
#pragma unroll
      for (int kb = 0; kb < 4; ++kb)
        z = __builtin_amdgcn_mfma_f32_16x16x32_bf16(a[kb], Bf[ty][kb], z, 0, 0, 0);
      acc[ty] = z;
    }
    float gi = acc[0][0], gf = acc[1][0], gg = acc[2][0], go = acc[3][0];
    c0 = sigf(gf) * c0 + sigf(gi) * tanh_(gg);
    float h = sigf(go) * tanh_(c0);
    unsigned short hb = f2bf(h);
    hA[(t + 1) & 1][(quad * 4) * DSTR + j] = hb;
    dhs[((size_t)t * BATCH + b0 + quad) * DHID + j] = hb;
    gx[0] = gxn[0]; gx[1] = gxn[1]; gx[2] = gxn[2]; gx[3] = gxn[3];
    __syncthreads();
  }
}

// ---------------------------------------------------------------------------
// logits[b][t][v] = dhs[t][b][:] . WdT[:][v] + fout[b][v];  f32 store.
// ---------------------------------------------------------------------------
__global__ __launch_bounds__(256) void k_logits(const unsigned short* __restrict__ dhs,
                                                const float* __restrict__ WdT,
                                                const float* __restrict__ fout,
                                                float* __restrict__ out) {
  __shared__ float s[DHID * 64];  // k-major: s[k*64 + m]
  int r0 = blockIdx.x * 64;
  int t = r0 / BATCH;
  int b0 = r0 % BATCH;
  int tid = threadIdx.x;
  for (int i = tid; i < 64 * DHID; i += 256) {
    int m = i >> 7;
    int k = i & 127;
    s[k * 64 + m] = bf2f(dhs[(size_t)(r0 + m) * DHID + k]);
  }
  __syncthreads();
  int v4 = tid & 63;
  int mg = tid >> 6;
  float4 acc[16];
#pragma unroll
  for (int m = 0; m < 16; ++m) acc[m] = make_float4(0.f, 0.f, 0.f, 0.f);
  for (int k = 0; k < DHID; ++k) {
    float4 wv = ((const float4*)(WdT + k * 256))[v4];
    const float4* sk = (const float4*)(s + k * 64 + mg * 16);
#pragma unroll
    for (int j = 0; j < 4; ++j) {
      float4 h4 = sk[j];
      acc[j * 4 + 0].x += h4.x * wv.x; acc[j * 4 + 0].y += h4.x * wv.y;
      acc[j * 4 + 0].z += h4.x * wv.z; acc[j * 4 + 0].w += h4.x * wv.w;
      acc[j * 4 + 1].x += h4.y * wv.x; acc[j * 4 + 1].y += h4.y * wv.y;
      acc[j * 4 + 1].z += h4.y * wv.z; acc[j * 4 + 1].w += h4.y * wv.w;
      acc[j * 4 + 2].x += h4.z * wv.x; acc[j * 4 + 2].y += h4.z * wv.y;
      acc[j * 4 + 2].z += h4.z * wv.z; acc[j * 4 + 2].w += h4.z * wv.w;
      acc[j * 4 + 3].x += h4.w * wv.x; acc[j * 4 + 3].y += h4.w * wv.y;
      acc[j * 4 + 3].z += h4.w * wv.z; acc[j * 4 + 3].w += h4.w * wv.w;
    }
  }
#pragma unroll
  for (int m = 0; m < 16; ++m) {
    int bb = b0 + mg * 16 + m;
    float4 fo = ((const float4*)(fout + bb * VOC))[v4];
    float4 r;
    r.x = acc[m].x + fo.x;
    r.y = acc[m].y + fo.y;
    r.z = acc[m].z + fo.z;
    r.w = acc[m].w + fo.w;
    ((float4*)(out + ((size_t)bb * TOUT + t) * VOC))[v4] = r;
  }
}

// ---------------------------------------------------------------------------
extern "C" void kernel_launch(void* const* d_in, const int* in_sizes, int n_in,
                              void* d_out, int out_size, void* d_ws, size_t ws_size,
                              hipStream_t stream) {
  const float* inp_onehot = (const float*)d_in[0];
  const float* zia     = (const float*)d_in[1];
  const float* tgt     = (const float*)d_in[2];
  const float* fortza  = (const float*)d_in[3];
  const float* enc_Wih = (const float*)d_in[4];
  const float* enc_Whh = (const float*)d_in[5];
  const float* enc_b   = (const float*)d_in[6];
  const float* sg_W    = (const float*)d_in[7];
  const float* sg_b    = (const float*)d_in[8];
  const float* Wc_W    = (const float*)d_in[9];
  const float* Wc_b    = (const float*)d_in[10];
  const float* dec_Wih = (const float*)d_in[11];
  const float* dec_Whh = (const float*)d_in[12];
  const float* dec_b   = (const float*)d_in[13];
  const float* out_W   = (const float*)d_in[14];
  const float* out_b   = (const float*)d_in[15];
  float* out = (float*)d_out;

  float* ws = (float*)d_ws;
  int* enc_idx  = (int*)d_ws;              // 131072 ints
  int* dec_idx  = enc_idx + BATCH * TIN;   //  65536 ints
  float* WxT    = ws + 196608;             //  65536 f
  float* WdecT  = ws + 262144;             // 131072 f
  float* WdT    = ws + 393216;             //  32768 f
  float* gxc    = ws + 425984;             // 131072 f
  float* h_enc  = ws + 557056;             //  32768 f
  float* dh0    = ws + 589824;             //  65536 f
  float* fout   = ws + 655360;             // 131072 f
  unsigned short* dhs = (unsigned short*)(ws + 786432);  // 8388608 u16; total ~19.9 MB

  k_prep<<<640, 512, 0, stream>>>(enc_Wih, enc_b, dec_Wih, dec_b, out_W, WxT, WdecT, WdT);
  k_findidx<<<BATCH * TIN / 4, 256, 0, stream>>>(inp_onehot, BATCH * TIN, enc_idx);
  k_findidx<<<BATCH * TOUT / 4, 256, 0, stream>>>(tgt, BATCH * TOUT, dec_idx);
  k_gx_const<<<BATCH, 256, 0, stream>>>(zia, enc_Wih, gxc);
  k_enc_scan_mfma<<<BATCH / 4, 256, 0, stream>>>(enc_Whh, WxT, gxc, enc_idx, h_enc);
  k_sg_fortza<<<BATCH, 256, 0, stream>>>(h_enc, fortza, sg_W, sg_b, out_W, out_b,
                                         out + (size_t)BATCH * TOUT * VOC, fout);
  k_dh0<<<BATCH, 128, 0, stream>>>(h_enc, zia, Wc_W, Wc_b, dh0);
  k_dec_scan_mfma<<<BATCH / 4, 512, 0, stream>>>(dec_Whh, WdecT, dec_idx, dh0, dhs);
  k_logits<<<TOUT * BATCH / 64, 256, 0, stream>>>(dhs, WdT, fout, out);
}